// Round 16
// baseline (19.143 us; speedup 1.0000x reference)
//
#include <hip/hip_runtime.h>
#include <hip/hip_bf16.h>

#define N_POINTS 16384
#define N_GAUSS  3200
#define N_CLASSES 14
#define NCHUNK (N_GAUSS / 32)   // 100 chunks of 32 gaussians

typedef _Float16 half8  __attribute__((ext_vector_type(8)));   // 4 VGPRs
typedef float    f32x4  __attribute__((ext_vector_type(4)));

// d_ws layout (294,400 B <= proven-safe 307,200):
//   [0, 204800)        crec: [3200][32] f16 -- K-slots [Ch(10)|Cl(10)|Ch(10)|0,0]
//   [204800, 294400)   semP: [14][3200] f16 -- chunk-permuted semantics
#define WS_CREC_OFF 0
#define WS_SEMP_OFF 204800

// ---------------------------------------------------------------------------
// Prep. C[10] quadratic-form coefficients (P-form):
//   arg = Sum_k P[k]*C[k],  P = [x^2,y^2,z^2,xy,xz,yz,x,y,z,1]
//   exp2(arg) = opacity * exp(-0.5*q)
// K=32 record packs all three precision terms of one contraction:
//   A = [Ch|Cl|Ch|00] x B = [Ph|Ph|Pl|00] -> Ch.Ph + Cl.Ph + Ch.Pl
// Semantics f16, permuted to PV K-order: p = grpW*8 + gt*4 + i <->
// g = c*32 + gt*16 + grpW*4 + i.
// ---------------------------------------------------------------------------
__global__ void gauss_prep_kernel(const float* __restrict__ means,
                                  const float* __restrict__ scales,
                                  const float* __restrict__ rotations,
                                  const float* __restrict__ opacities,
                                  const float* __restrict__ semantics,
                                  _Float16* __restrict__ crec,
                                  _Float16* __restrict__ semP) {
    const int g = blockIdx.x * blockDim.x + threadIdx.x;
    if (g >= N_GAUSS) return;

    float qw = rotations[g * 4 + 0];
    float qx = rotations[g * 4 + 1];
    float qy = rotations[g * 4 + 2];
    float qz = rotations[g * 4 + 3];
    float inv = 1.0f / sqrtf(qw * qw + qx * qx + qy * qy + qz * qz);
    qw *= inv; qx *= inv; qy *= inv; qz *= inv;

    float r00 = 1.0f - 2.0f * (qy * qy + qz * qz);
    float r01 = 2.0f * (qx * qy - qw * qz);
    float r02 = 2.0f * (qx * qz + qw * qy);
    float r10 = 2.0f * (qx * qy + qw * qz);
    float r11 = 1.0f - 2.0f * (qx * qx + qz * qz);
    float r12 = 2.0f * (qy * qz - qw * qx);
    float r20 = 2.0f * (qx * qz - qw * qy);
    float r21 = 2.0f * (qy * qz + qw * qx);
    float r22 = 1.0f - 2.0f * (qx * qx + qy * qy);

    float sx = scales[g * 3 + 0];
    float sy = scales[g * 3 + 1];
    float sz = scales[g * 3 + 2];
    float iv0 = 1.0f / (sx * sx);
    float iv1 = 1.0f / (sy * sy);
    float iv2 = 1.0f / (sz * sz);

    float a00 = iv0 * r00 * r00 + iv1 * r10 * r10 + iv2 * r20 * r20;
    float a01 = iv0 * r00 * r01 + iv1 * r10 * r11 + iv2 * r20 * r21;
    float a02 = iv0 * r00 * r02 + iv1 * r10 * r12 + iv2 * r20 * r22;
    float a11 = iv0 * r01 * r01 + iv1 * r11 * r11 + iv2 * r21 * r21;
    float a12 = iv0 * r01 * r02 + iv1 * r11 * r12 + iv2 * r21 * r22;
    float a22 = iv0 * r02 * r02 + iv1 * r12 * r12 + iv2 * r22 * r22;

    float mx = means[g * 3 + 0];
    float my = means[g * 3 + 1];
    float mz = means[g * 3 + 2];
    float amx = a00 * mx + a01 * my + a02 * mz;
    float amy = a01 * mx + a11 * my + a12 * mz;
    float amz = a02 * mx + a12 * my + a22 * mz;
    float muAmu = mx * amx + my * amy + mz * amz;

    const float k = -0.72134752044448170368f;   // -0.5 * log2(e)

    float C[10];
    C[0] = k * a00;  C[1] = k * a11;  C[2] = k * a22;
    C[3] = 2.0f * k * a01;  C[4] = 2.0f * k * a02;  C[5] = 2.0f * k * a12;
    C[6] = -2.0f * k * amx; C[7] = -2.0f * k * amy; C[8] = -2.0f * k * amz;
    C[9] = k * muAmu + log2f(opacities[g]);

    _Float16* rec = crec + (size_t)g * 32;
#pragma unroll
    for (int kk = 0; kk < 10; ++kk) {
        _Float16 h = (_Float16)C[kk];
        rec[kk]      = h;                              // Ch at K 0..9
        rec[10 + kk] = (_Float16)(C[kk] - (float)h);   // Cl at K 10..19
        rec[20 + kk] = h;                              // Ch again at K 20..29
    }
    rec[30] = (_Float16)0; rec[31] = (_Float16)0;

    const int cidx = g >> 5, r = g & 31;
    const int gt = r >> 4, grpW = (r >> 2) & 3, i = r & 3;
    const int p = grpW * 8 + gt * 4 + i;
#pragma unroll
    for (int c = 0; c < N_CLASSES; ++c)
        semP[(size_t)c * N_GAUSS + cidx * 32 + p] = (_Float16)semantics[g * N_CLASSES + c];
}

// ---------------------------------------------------------------------------
// Main: 256 blocks (1/CU) x 1024 threads (16 waves -> 4 waves/SIMD).
// R15 structure with a per-chunk instruction diet:
//  - w packed via v_cvt_pkrtz (1 instr/pair) instead of 32 scalar casts
//  - prefetch addresses advance by pointer-bump (crec +1024 f16, semP +32)
//  - unconditional c+1 prefetch (final garbage load stays inside d_ws,
//    never consumed)
// Per chunk (64 pts x 32 g): 8 Q-MFMAs ([Ch|Cl|Ch]x[Ph|Ph|Pl] one-shot
// 3-term), 32 exp2/lane, 16 pk-cvt, 4 swizzled b128 LDS writes, 4 A-frag
// reads + 4 PV MFMAs vs semP. Epilogue: LDS 16-way reduce + coalesced
// stores. No atomics, no zeroing.
// ---------------------------------------------------------------------------
__launch_bounds__(1024, 4)
__global__ void gauss_occ_main_kernel(const float* __restrict__ xyz,
                                      const _Float16* __restrict__ crec,
                                      const _Float16* __restrict__ semP,
                                      float* __restrict__ out) {
    __shared__ unsigned int wbuf[16][64][16];   // 64 KiB: per-wave 4 KiB tile

    const int tid  = threadIdx.x;
    const int lane = tid & 63;
    const int wid  = __builtin_amdgcn_readfirstlane(tid >> 6);   // 0..15
    const int pg   = blockIdx.x;                     // 0..255 point-group
    const int c0 = (wid * NCHUNK) >> 4;              // wid*6.25
    const int c1 = ((wid + 1) * NCHUNK) >> 4;

    const int m   = lane & 15;
    const int mm  = (m < N_CLASSES) ? m : (N_CLASSES - 1);
    const int grp = lane >> 4;
    const int frs = (m >> 1) & 3;          // swizzle key for rows s*16+m
    const int wsz = (lane >> 1) & 3;       // swizzle key for row lane

    const int pt = pg * 64 + lane;
    const float x = xyz[pt * 3 + 0];
    const float y = xyz[pt * 3 + 1];
    const float z = xyz[pt * 3 + 2];

    unsigned int (*wrow)[16] = wbuf[wid];

    // ---- one-time: stage expanded 32-slot B-row [Ph|Ph|Pl|00] per point ----
    {
        float P[10] = {x * x, y * y, z * z, x * y, x * z, y * z, x, y, z, 1.0f};
        _Float16 Ph[10], Pl[10];
#pragma unroll
        for (int j = 0; j < 10; ++j) {
            Ph[j] = (_Float16)P[j];
            Pl[j] = (_Float16)(P[j] - (float)Ph[j]);   // exact residual
        }
        half8 b0, b1, b2, b3;
#pragma unroll
        for (int j = 0; j < 8; ++j) b0[j] = Ph[j];                 // K0-7
        b1[0] = Ph[8]; b1[1] = Ph[9];
#pragma unroll
        for (int j = 0; j < 6; ++j) b1[2 + j] = Ph[j];             // K8-15
#pragma unroll
        for (int j = 0; j < 4; ++j) { b2[j] = Ph[6 + j]; b2[4 + j] = Pl[j]; }  // K16-23
#pragma unroll
        for (int j = 0; j < 6; ++j) b3[j] = Pl[4 + j];             // K24-29
        b3[6] = (_Float16)0; b3[7] = (_Float16)0;                  // K30-31
        *(half8*)&wrow[lane][(0 ^ wsz) * 4] = b0;
        *(half8*)&wrow[lane][(1 ^ wsz) * 4] = b1;
        *(half8*)&wrow[lane][(2 ^ wsz) * 4] = b2;
        *(half8*)&wrow[lane][(3 ^ wsz) * 4] = b3;
    }

    // gather Q B-fragments: lane (m,grp) needs block grp of point s*16+m
    half8 f1[4];
#pragma unroll
    for (int s = 0; s < 4; ++s)
        f1[s] = *(const half8*)&wrow[s * 16 + m][(grp ^ frs) * 4];

    f32x4 acc0 = {0.f, 0.f, 0.f, 0.f};
    f32x4 acc1 = {0.f, 0.f, 0.f, 0.f};
    f32x4 acc2 = {0.f, 0.f, 0.f, 0.f};
    f32x4 acc3 = {0.f, 0.f, 0.f, 0.f};
    const f32x4 z4 = {0.f, 0.f, 0.f, 0.f};

    // ---- software-pipelined main loop, pointer-bump prefetch ----
    const _Float16* pA = crec + ((size_t)(c0 * 32 + m)) * 32 + grp * 8;
    const _Float16* pB = semP + (size_t)mm * N_GAUSS + c0 * 32 + grp * 8;
    half8 A0 = *(const half8*)pA;
    half8 A1 = *(const half8*)(pA + 512);   // +16 gaussians x 32 slots
    half8 bS = *(const half8*)pB;

    for (int c = c0; c < c1; ++c) {
        pA += 1024;                          // next chunk: 32 gaussians x 32 slots
        pB += 32;
        const half8 nA0 = *(const half8*)pA;             // final-iter loads land
        const half8 nA1 = *(const half8*)(pA + 512);     // inside d_ws; unused
        const half8 nbS = *(const half8*)pB;

        // ---- Q-MFMAs + exp + pk-pack + staged write, per point-subtile s ----
#pragma unroll
        for (int s = 0; s < 4; ++s) {
            f32x4 t0 = __builtin_amdgcn_mfma_f32_16x16x32_f16(A0, f1[s], z4, 0, 0, 0);
            f32x4 t1 = __builtin_amdgcn_mfma_f32_16x16x32_f16(A1, f1[s], z4, 0, 0, 0);

            const float e0 = __builtin_amdgcn_exp2f(t0[0]);
            const float e1 = __builtin_amdgcn_exp2f(t0[1]);
            const float e2 = __builtin_amdgcn_exp2f(t0[2]);
            const float e3 = __builtin_amdgcn_exp2f(t0[3]);
            const float e4 = __builtin_amdgcn_exp2f(t1[0]);
            const float e5 = __builtin_amdgcn_exp2f(t1[1]);
            const float e6 = __builtin_amdgcn_exp2f(t1[2]);
            const float e7 = __builtin_amdgcn_exp2f(t1[3]);

            *(uint4*)&wrow[s * 16 + m][(grp ^ frs) * 4] = make_uint4(
                __builtin_bit_cast(unsigned int, __builtin_amdgcn_cvt_pkrtz(e0, e1)),
                __builtin_bit_cast(unsigned int, __builtin_amdgcn_cvt_pkrtz(e2, e3)),
                __builtin_bit_cast(unsigned int, __builtin_amdgcn_cvt_pkrtz(e4, e5)),
                __builtin_bit_cast(unsigned int, __builtin_amdgcn_cvt_pkrtz(e6, e7)));
        }

        // ---- PV-phase: A-frag reads + 4 MFMAs ----
        const half8 a0 = *(const half8*)&wrow[ 0 + m][(grp ^ frs) * 4];
        const half8 a1 = *(const half8*)&wrow[16 + m][(grp ^ frs) * 4];
        const half8 a2 = *(const half8*)&wrow[32 + m][(grp ^ frs) * 4];
        const half8 a3 = *(const half8*)&wrow[48 + m][(grp ^ frs) * 4];
        acc0 = __builtin_amdgcn_mfma_f32_16x16x32_f16(a0, bS, acc0, 0, 0, 0);
        acc1 = __builtin_amdgcn_mfma_f32_16x16x32_f16(a1, bS, acc1, 0, 0, 0);
        acc2 = __builtin_amdgcn_mfma_f32_16x16x32_f16(a2, bS, acc2, 0, 0, 0);
        acc3 = __builtin_amdgcn_mfma_f32_16x16x32_f16(a3, bS, acc3, 0, 0, 0);

        A0 = nA0; A1 = nA1; bS = nbS;
    }

    // ---- epilogue: dump acc into own LDS region, 16-way reduce, store ----
    float* red = (float*)&wbuf[0][0][0];   // [16][64][16] f32 view
#pragma unroll
    for (int i = 0; i < 4; ++i) {
        red[wid * 1024 + ( 0 + grp * 4 + i) * 16 + m] = acc0[i];
        red[wid * 1024 + (16 + grp * 4 + i) * 16 + m] = acc1[i];
        red[wid * 1024 + (32 + grp * 4 + i) * 16 + m] = acc2[i];
        red[wid * 1024 + (48 + grp * 4 + i) * 16 + m] = acc3[i];
    }
    __syncthreads();

    // 896 outputs per block; idx = l*14+cc -> address pg*896+idx: coalesced
    if (tid < 64 * N_CLASSES) {
        const int l = tid / N_CLASSES;
        const int cc = tid - l * N_CLASSES;
        float s = 0.0f;
#pragma unroll
        for (int wq = 0; wq < 16; ++wq) s += red[wq * 1024 + l * 16 + cc];
        out[(size_t)pg * (64 * N_CLASSES) + tid] = s;
    }
}

extern "C" void kernel_launch(void* const* d_in, const int* in_sizes, int n_in,
                              void* d_out, int out_size, void* d_ws, size_t ws_size,
                              hipStream_t stream) {
    const float* xyz       = (const float*)d_in[0];
    const float* means     = (const float*)d_in[1];
    const float* scales    = (const float*)d_in[2];
    const float* rotations = (const float*)d_in[3];
    const float* opacities = (const float*)d_in[4];
    const float* semantics = (const float*)d_in[5];
    float* out = (float*)d_out;

    _Float16* crec = (_Float16*)((char*)d_ws + WS_CREC_OFF);
    _Float16* semP = (_Float16*)((char*)d_ws + WS_SEMP_OFF);

    hipLaunchKernelGGL(gauss_prep_kernel,
                       dim3(13), dim3(256), 0, stream,
                       means, scales, rotations, opacities, semantics, crec, semP);

    hipLaunchKernelGGL(gauss_occ_main_kernel,
                       dim3(256), dim3(1024), 0, stream,
                       xyz, crec, semP, out);
}

// Round 17
// 18.617 us; speedup vs baseline: 1.0283x; 1.0283x over previous
//
#include <hip/hip_runtime.h>
#include <hip/hip_bf16.h>

#define N_POINTS 16384
#define N_GAUSS  3200
#define N_CLASSES 14
#define NCHUNK (N_GAUSS / 32)   // 100 chunks of 32 gaussians

typedef _Float16 half8  __attribute__((ext_vector_type(8)));   // 4 VGPRs
typedef float    f32x4  __attribute__((ext_vector_type(4)));

// d_ws layout (294,400 B <= proven-safe 307,200):
//   [0, 204800)        crec: [3200][32] f16 -- K-slots [Ch(10)|Cl(10)|Ch(10)|0,0]
//   [204800, 294400)   semP: [14][3200] f16 -- chunk-permuted semantics
#define WS_CREC_OFF 0
#define WS_SEMP_OFF 204800

// ---------------------------------------------------------------------------
// Prep. C[10] quadratic-form coefficients (P-form):
//   arg = Sum_k P[k]*C[k],  P = [x^2,y^2,z^2,xy,xz,yz,x,y,z,1]
//   exp2(arg) = opacity * exp(-0.5*q)
// K=32 record packs all three precision terms of one contraction:
//   A = [Ch|Cl|Ch|00] x B = [Ph|Ph|Pl|00] -> Ch.Ph + Cl.Ph + Ch.Pl
// Semantics f16, permuted to PV K-order: p = grpW*8 + gt*4 + i <->
// g = c*32 + gt*16 + grpW*4 + i.
// Launched 50 blocks x 64 threads (R16 ran 13 blocks -> 13 CUs; this spreads
// the latency-bound prep over 50 CUs).
// ---------------------------------------------------------------------------
__global__ void gauss_prep_kernel(const float* __restrict__ means,
                                  const float* __restrict__ scales,
                                  const float* __restrict__ rotations,
                                  const float* __restrict__ opacities,
                                  const float* __restrict__ semantics,
                                  _Float16* __restrict__ crec,
                                  _Float16* __restrict__ semP) {
    const int g = blockIdx.x * blockDim.x + threadIdx.x;
    if (g >= N_GAUSS) return;

    float qw = rotations[g * 4 + 0];
    float qx = rotations[g * 4 + 1];
    float qy = rotations[g * 4 + 2];
    float qz = rotations[g * 4 + 3];
    float inv = 1.0f / sqrtf(qw * qw + qx * qx + qy * qy + qz * qz);
    qw *= inv; qx *= inv; qy *= inv; qz *= inv;

    float r00 = 1.0f - 2.0f * (qy * qy + qz * qz);
    float r01 = 2.0f * (qx * qy - qw * qz);
    float r02 = 2.0f * (qx * qz + qw * qy);
    float r10 = 2.0f * (qx * qy + qw * qz);
    float r11 = 1.0f - 2.0f * (qx * qx + qz * qz);
    float r12 = 2.0f * (qy * qz - qw * qx);
    float r20 = 2.0f * (qx * qz - qw * qy);
    float r21 = 2.0f * (qy * qz + qw * qx);
    float r22 = 1.0f - 2.0f * (qx * qx + qy * qy);

    float sx = scales[g * 3 + 0];
    float sy = scales[g * 3 + 1];
    float sz = scales[g * 3 + 2];
    float iv0 = 1.0f / (sx * sx);
    float iv1 = 1.0f / (sy * sy);
    float iv2 = 1.0f / (sz * sz);

    float a00 = iv0 * r00 * r00 + iv1 * r10 * r10 + iv2 * r20 * r20;
    float a01 = iv0 * r00 * r01 + iv1 * r10 * r11 + iv2 * r20 * r21;
    float a02 = iv0 * r00 * r02 + iv1 * r10 * r12 + iv2 * r20 * r22;
    float a11 = iv0 * r01 * r01 + iv1 * r11 * r11 + iv2 * r21 * r21;
    float a12 = iv0 * r01 * r02 + iv1 * r11 * r12 + iv2 * r21 * r22;
    float a22 = iv0 * r02 * r02 + iv1 * r12 * r12 + iv2 * r22 * r22;

    float mx = means[g * 3 + 0];
    float my = means[g * 3 + 1];
    float mz = means[g * 3 + 2];
    float amx = a00 * mx + a01 * my + a02 * mz;
    float amy = a01 * mx + a11 * my + a12 * mz;
    float amz = a02 * mx + a12 * my + a22 * mz;
    float muAmu = mx * amx + my * amy + mz * amz;

    const float k = -0.72134752044448170368f;   // -0.5 * log2(e)

    float C[10];
    C[0] = k * a00;  C[1] = k * a11;  C[2] = k * a22;
    C[3] = 2.0f * k * a01;  C[4] = 2.0f * k * a02;  C[5] = 2.0f * k * a12;
    C[6] = -2.0f * k * amx; C[7] = -2.0f * k * amy; C[8] = -2.0f * k * amz;
    C[9] = k * muAmu + log2f(opacities[g]);

    _Float16* rec = crec + (size_t)g * 32;
#pragma unroll
    for (int kk = 0; kk < 10; ++kk) {
        _Float16 h = (_Float16)C[kk];
        rec[kk]      = h;                              // Ch at K 0..9
        rec[10 + kk] = (_Float16)(C[kk] - (float)h);   // Cl at K 10..19
        rec[20 + kk] = h;                              // Ch again at K 20..29
    }
    rec[30] = (_Float16)0; rec[31] = (_Float16)0;

    const int cidx = g >> 5, r = g & 31;
    const int gt = r >> 4, grpW = (r >> 2) & 3, i = r & 3;
    const int p = grpW * 8 + gt * 4 + i;
#pragma unroll
    for (int c = 0; c < N_CLASSES; ++c)
        semP[(size_t)c * N_GAUSS + cidx * 32 + p] = (_Float16)semantics[g * N_CLASSES + c];
}

// ---------------------------------------------------------------------------
// Main: 256 blocks (1/CU) x 1024 threads (16 waves -> 4 waves/SIMD).
// WORK BALANCE (new vs R16): 100 chunks over 16 waves = 6.25. R16's
// c0=(wid*100)>>4 put the four 7-chunk waves at wids {3,7,11,15} -- under a
// wid%4 wave->SIMD mapping ALL FOUR land on SIMD 3 (28 vs 24 chunks, ~12%
// block tail). Re-placing the 7-chunk waves at wids {3,6,9,12} spreads them
// across SIMDs under BOTH candidate mappings (%4 -> 3,2,1,0; /4 -> 0,1,2,3).
// Per chunk (64 pts x 32 g): 8 Q-MFMAs ([Ch|Cl|Ch]x[Ph|Ph|Pl] one-shot
// 3-term), 32 exp2/lane, 16 pk-cvt (RTZ), 4 swizzled b128 LDS writes,
// 4 A-frag reads + 4 PV MFMAs vs semP; pointer-bump prefetch (final-iter
// prefetch lands inside d_ws, never consumed). Epilogue: LDS 16-way reduce
// + coalesced stores. No atomics, no zeroing.
// ---------------------------------------------------------------------------
__launch_bounds__(1024, 4)
__global__ void gauss_occ_main_kernel(const float* __restrict__ xyz,
                                      const _Float16* __restrict__ crec,
                                      const _Float16* __restrict__ semP,
                                      float* __restrict__ out) {
    __shared__ unsigned int wbuf[16][64][16];   // 64 KiB: per-wave 4 KiB tile

    const int tid  = threadIdx.x;
    const int lane = tid & 63;
    const int wid  = __builtin_amdgcn_readfirstlane(tid >> 6);   // 0..15
    const int pg   = blockIdx.x;                     // 0..255 point-group

    // balanced chunk ranges: 6 chunks/wave, +1 extra at wids 3,6,9,12
    const int c0 = 6 * wid + (wid >= 4) + (wid >= 7) + (wid >= 10) + (wid >= 13);
    const int cnt = 6 + ((wid == 3) | (wid == 6) | (wid == 9) | (wid == 12));
    const int c1 = c0 + cnt;

    const int m   = lane & 15;
    const int mm  = (m < N_CLASSES) ? m : (N_CLASSES - 1);
    const int grp = lane >> 4;
    const int frs = (m >> 1) & 3;          // swizzle key for rows s*16+m
    const int wsz = (lane >> 1) & 3;       // swizzle key for row lane

    const int pt = pg * 64 + lane;
    const float x = xyz[pt * 3 + 0];
    const float y = xyz[pt * 3 + 1];
    const float z = xyz[pt * 3 + 2];

    unsigned int (*wrow)[16] = wbuf[wid];

    // ---- one-time: stage expanded 32-slot B-row [Ph|Ph|Pl|00] per point ----
    {
        float P[10] = {x * x, y * y, z * z, x * y, x * z, y * z, x, y, z, 1.0f};
        _Float16 Ph[10], Pl[10];
#pragma unroll
        for (int j = 0; j < 10; ++j) {
            Ph[j] = (_Float16)P[j];
            Pl[j] = (_Float16)(P[j] - (float)Ph[j]);   // exact residual
        }
        half8 b0, b1, b2, b3;
#pragma unroll
        for (int j = 0; j < 8; ++j) b0[j] = Ph[j];                 // K0-7
        b1[0] = Ph[8]; b1[1] = Ph[9];
#pragma unroll
        for (int j = 0; j < 6; ++j) b1[2 + j] = Ph[j];             // K8-15
#pragma unroll
        for (int j = 0; j < 4; ++j) { b2[j] = Ph[6 + j]; b2[4 + j] = Pl[j]; }  // K16-23
#pragma unroll
        for (int j = 0; j < 6; ++j) b3[j] = Pl[4 + j];             // K24-29
        b3[6] = (_Float16)0; b3[7] = (_Float16)0;                  // K30-31
        *(half8*)&wrow[lane][(0 ^ wsz) * 4] = b0;
        *(half8*)&wrow[lane][(1 ^ wsz) * 4] = b1;
        *(half8*)&wrow[lane][(2 ^ wsz) * 4] = b2;
        *(half8*)&wrow[lane][(3 ^ wsz) * 4] = b3;
    }

    // gather Q B-fragments: lane (m,grp) needs block grp of point s*16+m
    half8 f1[4];
#pragma unroll
    for (int s = 0; s < 4; ++s)
        f1[s] = *(const half8*)&wrow[s * 16 + m][(grp ^ frs) * 4];

    f32x4 acc0 = {0.f, 0.f, 0.f, 0.f};
    f32x4 acc1 = {0.f, 0.f, 0.f, 0.f};
    f32x4 acc2 = {0.f, 0.f, 0.f, 0.f};
    f32x4 acc3 = {0.f, 0.f, 0.f, 0.f};
    const f32x4 z4 = {0.f, 0.f, 0.f, 0.f};

    // ---- software-pipelined main loop, pointer-bump prefetch ----
    const _Float16* pA = crec + ((size_t)(c0 * 32 + m)) * 32 + grp * 8;
    const _Float16* pB = semP + (size_t)mm * N_GAUSS + c0 * 32 + grp * 8;
    half8 A0 = *(const half8*)pA;
    half8 A1 = *(const half8*)(pA + 512);   // +16 gaussians x 32 slots
    half8 bS = *(const half8*)pB;

    for (int c = c0; c < c1; ++c) {
        pA += 1024;                          // next chunk: 32 gaussians x 32 slots
        pB += 32;
        const half8 nA0 = *(const half8*)pA;             // final-iter loads land
        const half8 nA1 = *(const half8*)(pA + 512);     // inside d_ws; unused
        const half8 nbS = *(const half8*)pB;

        // ---- Q-MFMAs + exp + pk-pack + staged write, per point-subtile s ----
#pragma unroll
        for (int s = 0; s < 4; ++s) {
            f32x4 t0 = __builtin_amdgcn_mfma_f32_16x16x32_f16(A0, f1[s], z4, 0, 0, 0);
            f32x4 t1 = __builtin_amdgcn_mfma_f32_16x16x32_f16(A1, f1[s], z4, 0, 0, 0);

            const float e0 = __builtin_amdgcn_exp2f(t0[0]);
            const float e1 = __builtin_amdgcn_exp2f(t0[1]);
            const float e2 = __builtin_amdgcn_exp2f(t0[2]);
            const float e3 = __builtin_amdgcn_exp2f(t0[3]);
            const float e4 = __builtin_amdgcn_exp2f(t1[0]);
            const float e5 = __builtin_amdgcn_exp2f(t1[1]);
            const float e6 = __builtin_amdgcn_exp2f(t1[2]);
            const float e7 = __builtin_amdgcn_exp2f(t1[3]);

            *(uint4*)&wrow[s * 16 + m][(grp ^ frs) * 4] = make_uint4(
                __builtin_bit_cast(unsigned int, __builtin_amdgcn_cvt_pkrtz(e0, e1)),
                __builtin_bit_cast(unsigned int, __builtin_amdgcn_cvt_pkrtz(e2, e3)),
                __builtin_bit_cast(unsigned int, __builtin_amdgcn_cvt_pkrtz(e4, e5)),
                __builtin_bit_cast(unsigned int, __builtin_amdgcn_cvt_pkrtz(e6, e7)));
        }

        // ---- PV-phase: A-frag reads + 4 MFMAs ----
        const half8 a0 = *(const half8*)&wrow[ 0 + m][(grp ^ frs) * 4];
        const half8 a1 = *(const half8*)&wrow[16 + m][(grp ^ frs) * 4];
        const half8 a2 = *(const half8*)&wrow[32 + m][(grp ^ frs) * 4];
        const half8 a3 = *(const half8*)&wrow[48 + m][(grp ^ frs) * 4];
        acc0 = __builtin_amdgcn_mfma_f32_16x16x32_f16(a0, bS, acc0, 0, 0, 0);
        acc1 = __builtin_amdgcn_mfma_f32_16x16x32_f16(a1, bS, acc1, 0, 0, 0);
        acc2 = __builtin_amdgcn_mfma_f32_16x16x32_f16(a2, bS, acc2, 0, 0, 0);
        acc3 = __builtin_amdgcn_mfma_f32_16x16x32_f16(a3, bS, acc3, 0, 0, 0);

        A0 = nA0; A1 = nA1; bS = nbS;
    }

    // ---- epilogue: dump acc into own LDS region, 16-way reduce, store ----
    float* red = (float*)&wbuf[0][0][0];   // [16][64][16] f32 view
#pragma unroll
    for (int i = 0; i < 4; ++i) {
        red[wid * 1024 + ( 0 + grp * 4 + i) * 16 + m] = acc0[i];
        red[wid * 1024 + (16 + grp * 4 + i) * 16 + m] = acc1[i];
        red[wid * 1024 + (32 + grp * 4 + i) * 16 + m] = acc2[i];
        red[wid * 1024 + (48 + grp * 4 + i) * 16 + m] = acc3[i];
    }
    __syncthreads();

    // 896 outputs per block; idx = l*14+cc -> address pg*896+idx: coalesced
    if (tid < 64 * N_CLASSES) {
        const int l = tid / N_CLASSES;
        const int cc = tid - l * N_CLASSES;
        float s = 0.0f;
#pragma unroll
        for (int wq = 0; wq < 16; ++wq) s += red[wq * 1024 + l * 16 + cc];
        out[(size_t)pg * (64 * N_CLASSES) + tid] = s;
    }
}

extern "C" void kernel_launch(void* const* d_in, const int* in_sizes, int n_in,
                              void* d_out, int out_size, void* d_ws, size_t ws_size,
                              hipStream_t stream) {
    const float* xyz       = (const float*)d_in[0];
    const float* means     = (const float*)d_in[1];
    const float* scales    = (const float*)d_in[2];
    const float* rotations = (const float*)d_in[3];
    const float* opacities = (const float*)d_in[4];
    const float* semantics = (const float*)d_in[5];
    float* out = (float*)d_out;

    _Float16* crec = (_Float16*)((char*)d_ws + WS_CREC_OFF);
    _Float16* semP = (_Float16*)((char*)d_ws + WS_SEMP_OFF);

    hipLaunchKernelGGL(gauss_prep_kernel,
                       dim3(50), dim3(64), 0, stream,
                       means, scales, rotations, opacities, semantics, crec, semP);

    hipLaunchKernelGGL(gauss_occ_main_kernel,
                       dim3(256), dim3(1024), 0, stream,
                       xyz, crec, semP, out);
}